// Round 18
// baseline (112.470 us; speedup 1.0000x reference)
//
#include <hip/hip_runtime.h>

#define MARGIN 0.0625f

// Problem sizes (fixed by the reference)
#define P 4096        // 64*64 query points
#define M 100000      // means

// Grid: threshold distance sqrt(MARGIN) = 0.25; cell = 0.25 so the
// 27-neighborhood of a query's (clamped) cell contains every mean with
// |q-m|inf <= 0.25, hence every mean that can have d^2 < MARGIN. Points
// outside the extent clamp into border cells; clamping is per-axis
// monotone & 1-Lipschitz so the coverage guarantee survives. Extra /
// duplicate candidates are harmless for a min; zero candidates => true
// min >= MARGIN => relu contribution 0. Bit-exact rounds 7/8/10-13/15-17.
#define NC 36
#define NCELLS (NC * NC * NC)   // 46656
#define GMIN (-4.5f)
#define INVC 4.0f               // 1 / 0.25

// Fixed-capacity buckets (ws is 256 MiB): 46656 cells x 256 x 16 B = 191 MB.
// Max observed cell count ~150 << 256; slot<CAP guard + min(cnt,CAP) keep
// accesses in-range regardless of data.
#define CAP 256

typedef float float4v __attribute__((ext_vector_type(4)));

// ws layout (bytes):
//   cnt: uint[NCELLS]          @ 0        (186,624 B; zeroed by memset)
//   bucket: float4[NCELLS*CAP] @ 186,880  (191,102,976 B)
#define WS_CNT_OFF    0
#define WS_BUCKET_OFF 186880

static __device__ __forceinline__ int cell1(float v) {
    int c = (int)floorf((v - GMIN) * INVC);
    return min(max(c, 0), NC - 1);
}

// ---------------------------------------------------------------------------
// Kernel 1: scatter means into per-cell buckets (-2x,-2y,-2z,|m|^2 --
// bit-identical transform chain to all prior rounds; identical to the
// round-11 scatter). Also zeroes out[0] (stream-ordered before query).
// ---------------------------------------------------------------------------
__global__ __launch_bounds__(256) void scatter_kernel(
    const float* __restrict__ means,
    unsigned int* __restrict__ cnt,
    float4v* __restrict__ bucket,
    float* __restrict__ out)
{
    int idx = blockIdx.x * 256 + threadIdx.x;
    if (idx == 0) out[0] = 0.0f;
    if (idx < M) {
        const float* mp = means + 3 * idx;
        float x = mp[0], y = mp[1], z = mp[2];
        int c = (cell1(z) * NC + cell1(y)) * NC + cell1(x);
        unsigned int slot = atomicAdd(&cnt[c], 1u);
        if (slot < CAP)
            bucket[(size_t)c * CAP + slot] =
                (float4v){-2.0f * x, -2.0f * y, -2.0f * z,
                          fmaf(x, x, fmaf(y, y, z * z))};
    }
}

// ---------------------------------------------------------------------------
// Kernel 2: query + loss. The UN-CONFOUNDED TLP experiment: r17's exact
// gather structure (grouped x-row issue, single-group 27-count prefetch,
// XCD chunk swizzle) at DOUBLE the residency. 128-thread blocks (2 waves,
// 1 wave = 1 query), grid 2048, __launch_bounds__(128,8) -> 16 blocks/CU
// x 2 waves = 32 waves/CU (r11-r17 all ran 16). VGPR diet to fit the
// 64-reg cap: lb-pruning dropped (measured null r15/r17), c27[] dropped
// (row addresses recomputed per group from kx/ky/kz).
// Exactness: candidate superset (no pruning), clamped-slot duplicates
// (validated since r10), neutral-masked uses (r16/r17), identical fmaf
// chain -> absmax 0.
// ---------------------------------------------------------------------------
__global__ __launch_bounds__(128, 8) void query_kernel(
    const float* __restrict__ outputs,   // [P*3]
    const float* __restrict__ c2ws,      // [64*16]
    const float* __restrict__ scales,    // [64]
    const unsigned int* __restrict__ cnt,
    const float4v* __restrict__ bucket,
    float* __restrict__ out)
{
    const int t    = threadIdx.x;
    const int lane = t & 63;
    const int wid  = t >> 6;             // 0..1
    // 2048 blocks = 8 XCDs x 256: chunk consecutive qb onto one XCD so
    // same-trajectory queries (shared cells) hit the same L2.
    const int bid = (int)blockIdx.x;
    const int qb  = (bid & 7) * 256 + (bid >> 3);
    const int qi  = qb * 2 + wid;

    // ---- query transform (all lanes redundantly; scalar-broadcast) ----
    const int b = qi >> 6;
    const float s  = scales[b];
    const float o0 = outputs[3 * qi + 0];
    const float o1 = outputs[3 * qi + 1];
    const float o2 = outputs[3 * qi + 2];
    const float* cw = c2ws + b * 16;
    float q0 = fmaf(s, fmaf(cw[0],  o0, fmaf(cw[1],  o1, cw[2]  * o2)), cw[3]);
    float q1 = fmaf(s, fmaf(cw[4],  o0, fmaf(cw[5],  o1, cw[6]  * o2)), cw[7]);
    float q2 = fmaf(s, fmaf(cw[8],  o0, fmaf(cw[9],  o1, cw[10] * o2)), cw[11]);
    float qq = fmaf(q0, q0, fmaf(q1, q1, q2 * q2));

    const int cx = cell1(q0), cy = cell1(q1), cz = cell1(q2);

    // per-axis clamped neighbor indices (no box distances: pruning dropped)
    int kx[3], ky[3], kz[3];
#pragma unroll
    for (int o = 0; o < 3; ++o) {
        kx[o] = min(max(cx + o - 1, 0), NC - 1);
        ky[o] = min(max(cy + o - 1, 0), NC - 1);
        kz[o] = min(max(cz + o - 1, 0), NC - 1);
    }

    // ---- prefetch all 27 counts (independent loads, one wait) ----
    int n27[27];
#pragma unroll
    for (int j = 0; j < 27; ++j) {
        const int iz = j / 9, iy = (j / 3) % 3, ix = j % 3;   // static
        n27[j] = min((int)cnt[(kz[iz] * NC + ky[iy]) * NC + kx[ix]], CAP);
    }

#define NEUT ((float4v){0.0f, 0.0f, 0.0f, 1e30f})
#define DVAL(mv) fmaf(q2, (mv)[2], fmaf(q1, (mv)[1], fmaf(q0, (mv)[0], (mv)[3])))

    float mnA = 1e30f, mnB = 1e30f;
#pragma unroll
    for (int g = 0; g < 9; ++g) {
        const int j0 = g * 3;                       // static
        const int n0 = n27[j0], n1 = n27[j0 + 1], n2 = n27[j0 + 2];
        if ((n0 | n1 | n2) > 0) {                   // wave-uniform
            const int iz = g / 3, iy = g % 3;       // static
            const size_t cb = (size_t)((kz[iz] * NC + ky[iy]) * NC);
            const float4v* r0 = bucket + (cb + kx[0]) * CAP;
            const float4v* r1 = bucket + (cb + kx[1]) * CAP;
            const float4v* r2 = bucket + (cb + kx[2]) * CAP;
            // round 0: conditional loads (no extra traffic), issued
            // back-to-back; unconditional neutral-masked uses.
            float4v mv0 = NEUT, mv1 = NEUT, mv2 = NEUT;
            if (n0 > 0) mv0 = r0[min(lane, n0 - 1)];
            if (n1 > 0) mv1 = r1[min(lane, n1 - 1)];
            if (n2 > 0) mv2 = r2[min(lane, n2 - 1)];
            mnA = fminf(mnA, DVAL(mv0));
            mnB = fminf(mnB, DVAL(mv1));
            mnA = fminf(mnA, DVAL(mv2));
            // round 1: slots 64.., same pattern (clamped dup slots exact)
            if ((n0 > 64) | (n1 > 64) | (n2 > 64)) {    // wave-uniform
                float4v w0 = NEUT, w1 = NEUT, w2 = NEUT;
                if (n0 > 64) w0 = r0[min(64 + lane, n0 - 1)];
                if (n1 > 64) w1 = r1[min(64 + lane, n1 - 1)];
                if (n2 > 64) w2 = r2[min(64 + lane, n2 - 1)];
                mnA = fminf(mnA, DVAL(w0));
                mnB = fminf(mnB, DVAL(w1));
                mnA = fminf(mnA, DVAL(w2));
            }
            // round 2: rare dense cells (n>128), branchy
            if ((n0 > 128) | (n1 > 128) | (n2 > 128)) { // wave-uniform
                if (n0 > 128)
                    for (int k = 128 + lane; k < n0; k += 64)
                        mnA = fminf(mnA, DVAL(r0[k]));
                if (n1 > 128)
                    for (int k = 128 + lane; k < n1; k += 64)
                        mnB = fminf(mnB, DVAL(r1[k]));
                if (n2 > 128)
                    for (int k = 128 + lane; k < n2; k += 64)
                        mnA = fminf(mnA, DVAL(r2[k]));
            }
        }
    }
#undef NEUT
#undef DVAL

    float mn = fminf(mnA, mnB);
    // ---- fold 64 lanes ----
#pragma unroll
    for (int off = 32; off > 0; off >>= 1)
        mn = fminf(mn, __shfl_xor(mn, off, 64));

    float v = 0.0f;
    if (lane == 0) {
        float d = fmaxf(qq + mn, 0.0f);   // empty neighborhood -> relu 0
        v = fmaxf(MARGIN - d, 0.0f) * (1.0f / (float)P);
    }

    // ---- block reduction (2 wave leaders), one atomicAdd per block ----
    __shared__ float red[2];
    if (lane == 0) red[wid] = v;
    __syncthreads();
    if (t == 0)
        atomicAdd(out, red[0] + red[1]);
}

extern "C" void kernel_launch(void* const* d_in, const int* in_sizes, int n_in,
                              void* d_out, int out_size, void* d_ws, size_t ws_size,
                              hipStream_t stream) {
    const float* outputs = (const float*)d_in[0];  // (64,64,3)
    const float* c2ws    = (const float*)d_in[1];  // (64,4,4)
    const float* scales  = (const float*)d_in[2];  // (64,)
    const float* means   = (const float*)d_in[3];  // (100000,3)

    char* ws = (char*)d_ws;
    unsigned int* cnt    = (unsigned int*)(ws + WS_CNT_OFF);
    float4v*      bucket = (float4v*)(ws + WS_BUCKET_OFF);
    float*        out    = (float*)d_out;

    hipMemsetAsync(cnt, 0, NCELLS * sizeof(unsigned int), stream);
    scatter_kernel<<<(M + 255) / 256, 256, 0, stream>>>(means, cnt, bucket, out);
    query_kernel<<<P / 2, 128, 0, stream>>>(outputs, c2ws, scales,
                                            cnt, bucket, out);
}

// Round 19
// 94.779 us; speedup vs baseline: 1.1867x; 1.1867x over previous
//
#include <hip/hip_runtime.h>

#define MARGIN 0.0625f

// Problem sizes (fixed by the reference)
#define P 4096        // 64*64 query points
#define M 100000      // means

// Grid: threshold distance sqrt(MARGIN) = 0.25; cell = 0.25 so the
// 27-neighborhood of a query's (clamped) cell contains every mean with
// |q-m|inf <= 0.25, hence every mean that can have d^2 < MARGIN. Points
// outside the extent clamp into border cells; clamping is per-axis
// monotone & 1-Lipschitz so the coverage guarantee survives. Extra /
// duplicate candidates are harmless for a min; zero candidates => true
// min >= MARGIN => relu contribution 0. Bit-exact rounds 7/8/10-13/15-18.
#define NC 36
#define NCELLS (NC * NC * NC)   // 46656
#define GMIN (-4.5f)
#define INVC 4.0f               // 1 / 0.25

// Fixed-capacity buckets (ws is 256 MiB): 46656 cells x 256 x 16 B = 191 MB.
// Max observed cell count ~150 << 256; slot<CAP guard + min(cnt,CAP) keep
// accesses in-range regardless of data.
#define CAP 256

typedef float float4v __attribute__((ext_vector_type(4)));

// ws layout (bytes):
//   cnt: uint[NCELLS]          @ 0        (186,624 B; zeroed by memset)
//   bucket: float4[NCELLS*CAP] @ 186,880  (191,102,976 B)
#define WS_CNT_OFF    0
#define WS_BUCKET_OFF 186880

static __device__ __forceinline__ int cell1(float v) {
    int c = (int)floorf((v - GMIN) * INVC);
    return min(max(c, 0), NC - 1);
}

// ---------------------------------------------------------------------------
// Kernel 1: scatter means into per-cell buckets (-2x,-2y,-2z,|m|^2 --
// bit-identical transform chain to all prior rounds; identical to the
// round-11 scatter, which measured 93.6 total). Also zeroes out[0]
// (stream-ordered before query_kernel's atomicAdds).
// ---------------------------------------------------------------------------
__global__ __launch_bounds__(256) void scatter_kernel(
    const float* __restrict__ means,
    unsigned int* __restrict__ cnt,
    float4v* __restrict__ bucket,
    float* __restrict__ out)
{
    int idx = blockIdx.x * 256 + threadIdx.x;
    if (idx == 0) out[0] = 0.0f;
    if (idx < M) {
        const float* mp = means + 3 * idx;
        float x = mp[0], y = mp[1], z = mp[2];
        int c = (cell1(z) * NC + cell1(y)) * NC + cell1(x);
        unsigned int slot = atomicAdd(&cnt[c], 1u);
        if (slot < CAP)
            bucket[(size_t)c * CAP + slot] =
                (float4v){-2.0f * x, -2.0f * y, -2.0f * z,
                          fmaf(x, x, fmaf(y, y, z * z))};
    }
}

// ---------------------------------------------------------------------------
// Kernel 2: query + loss. EXACT round-11 kernel body (the measured best:
// 1 wave/query, 4 queries/256-block, (256,4), single-group 27-count
// prefetch, branchy clamped-slot gathers) with ONE change: the query->wave
// MAPPING. r11 packed 4 consecutive queries (same trajectory batch ->
// same dense cells) per block and chunked blocks per XCD -- so the dense
// central batches landed concentrated, and the wall time was their tail
// (r12 counters: time-avg occupancy ~21%, i.e. most waves done while a
// few grind). New mapping: qi = bid + wid*1024 -- each block's 4 waves
// come from 4 DIFFERENT batches (uncorrelated density -> max-of-4 is
// balanced) and consecutive blocks round-robin across all CUs/XCDs (no
// CU inherits a dense streak). Candidate set per query unchanged ->
// absmax 0.
// ---------------------------------------------------------------------------
__global__ __launch_bounds__(256, 4) void query_kernel(
    const float* __restrict__ outputs,   // [P*3]
    const float* __restrict__ c2ws,      // [64*16]
    const float* __restrict__ scales,    // [64]
    const unsigned int* __restrict__ cnt,
    const float4v* __restrict__ bucket,
    float* __restrict__ out)
{
    const int t    = threadIdx.x;
    const int lane = t & 63;
    // balance-first mapping: 4 waves of a block take queries 1024 apart
    // (different batches); blocks round-robin the batch interior.
    const int qi = (int)blockIdx.x + (t >> 6) * 1024;

    // ---- query transform (all lanes redundantly; scalar-broadcast) ----
    const int b = qi >> 6;
    const float s  = scales[b];
    const float o0 = outputs[3 * qi + 0];
    const float o1 = outputs[3 * qi + 1];
    const float o2 = outputs[3 * qi + 2];
    const float* cw = c2ws + b * 16;
    float q0 = fmaf(s, fmaf(cw[0],  o0, fmaf(cw[1],  o1, cw[2]  * o2)), cw[3]);
    float q1 = fmaf(s, fmaf(cw[4],  o0, fmaf(cw[5],  o1, cw[6]  * o2)), cw[7]);
    float q2 = fmaf(s, fmaf(cw[8],  o0, fmaf(cw[9],  o1, cw[10] * o2)), cw[11]);
    float qq = fmaf(q0, q0, fmaf(q1, q1, q2 * q2));

    // ---- candidate scan over 27-cell neighborhood ----
    const int cx = cell1(q0), cy = cell1(q1), cz = cell1(q2);

    // per-axis clamped neighbor indices
    int kx[3], ky[3], kz[3];
#pragma unroll
    for (int o = 0; o < 3; ++o) {
        kx[o] = min(max(cx + o - 1, 0), NC - 1);
        ky[o] = min(max(cy + o - 1, 0), NC - 1);
        kz[o] = min(max(cz + o - 1, 0), NC - 1);
    }

    // ---- prefetch all 27 cell ids + counts (independent loads, one wait)
    int c27[27];
#pragma unroll
    for (int j = 0; j < 27; ++j) {
        const int iz = j / 9, iy = (j / 3) % 3, ix = j % 3;   // static
        c27[j] = (kz[iz] * NC + ky[iy]) * NC + kx[ix];
    }
    int n27[27];
#pragma unroll
    for (int j = 0; j < 27; ++j)
        n27[j] = min((int)cnt[c27[j]], CAP);

    int tot = 0;
#pragma unroll
    for (int j = 0; j < 27; ++j) tot += n27[j];

    float mn = 1e30f;
    if (tot > 0) {      // wave-uniform (all inputs identical across lanes)
#pragma unroll
        for (int j = 0; j < 27; ++j) {
            const int n = n27[j];
            if (n == 0) continue;                   // wave-uniform
            const float4v* row = bucket + (size_t)c27[j] * CAP;
            // round 0: clamped slot (always a written slot when n>0;
            // duplicates are real candidates -> exact for min)
            {
                float4v mv = row[min(lane, n - 1)];
                mn = fminf(mn, fmaf(q2, mv[2], fmaf(q1, mv[1],
                               fmaf(q0, mv[0], mv[3]))));
            }
            if (n > 64) {                           // wave-uniform
                float4v mv = row[min(64 + lane, n - 1)];
                mn = fminf(mn, fmaf(q2, mv[2], fmaf(q1, mv[1],
                               fmaf(q0, mv[0], mv[3]))));
            }
            if (n > 128) {                          // rare dense cells
                for (int k = 128 + lane; k < n; k += 64) {
                    float4v mv = row[k];
                    mn = fminf(mn, fmaf(q2, mv[2], fmaf(q1, mv[1],
                                   fmaf(q0, mv[0], mv[3]))));
                }
            }
        }
        // ---- fold 64 lanes ----
#pragma unroll
        for (int off = 32; off > 0; off >>= 1)
            mn = fminf(mn, __shfl_xor(mn, off, 64));
    }

    float v = 0.0f;
    if (lane == 0) {
        float d = fmaxf(qq + mn, 0.0f);   // empty neighborhood -> relu 0
        v = fmaxf(MARGIN - d, 0.0f) * (1.0f / (float)P);
    }

    // ---- block reduction (4 wave leaders), one atomicAdd per block ----
    __shared__ float red[4];
    if (lane == 0) red[t >> 6] = v;
    __syncthreads();
    if (t == 0)
        atomicAdd(out, red[0] + red[1] + red[2] + red[3]);
}

extern "C" void kernel_launch(void* const* d_in, const int* in_sizes, int n_in,
                              void* d_out, int out_size, void* d_ws, size_t ws_size,
                              hipStream_t stream) {
    const float* outputs = (const float*)d_in[0];  // (64,64,3)
    const float* c2ws    = (const float*)d_in[1];  // (64,4,4)
    const float* scales  = (const float*)d_in[2];  // (64,)
    const float* means   = (const float*)d_in[3];  // (100000,3)

    char* ws = (char*)d_ws;
    unsigned int* cnt    = (unsigned int*)(ws + WS_CNT_OFF);
    float4v*      bucket = (float4v*)(ws + WS_BUCKET_OFF);
    float*        out    = (float*)d_out;

    hipMemsetAsync(cnt, 0, NCELLS * sizeof(unsigned int), stream);
    scatter_kernel<<<(M + 255) / 256, 256, 0, stream>>>(means, cnt, bucket, out);
    query_kernel<<<P / 4, 256, 0, stream>>>(outputs, c2ws, scales,
                                            cnt, bucket, out);
}

// Round 20
// 92.452 us; speedup vs baseline: 1.2165x; 1.0252x over previous
//
#include <hip/hip_runtime.h>

#define MARGIN 0.0625f

// Problem sizes (fixed by the reference)
#define P 4096        // 64*64 query points
#define M 100000      // means

// Grid: threshold distance sqrt(MARGIN) = 0.25; cell = 0.25 so the
// 27-neighborhood of a query's (clamped) cell contains every mean with
// |q-m|inf <= 0.25, hence every mean that can have d^2 < MARGIN. Points
// outside the extent clamp into border cells; clamping is per-axis
// monotone & 1-Lipschitz so the coverage guarantee survives. Extra /
// duplicate candidates are harmless for a min; zero candidates => true
// min >= MARGIN => relu contribution 0. Bit-exact rounds 7/8/10-13/15-19.
//
// FINAL CONFIGURATION (round 20): the r11 structure, best-measured at
// 93.58 us. Campaign summary: issue-structure (branchy/branch-free/
// grouped), lb-pruning, TLP (3 variants), and load-balance mapping were
// each isolated and measured -- all land in [93.6, 94.8] or regress.
// Budget: harness poison fill ~41 us (82-84% HBM peak, fixed), dispatch
// gaps + memset ~15 us (fusion via cooperative/last-block-done crashed
// the container, r3/r9), scatter ~7 us, query ~25 us (latency-bound,
// invariant under all four axes).
#define NC 36
#define NCELLS (NC * NC * NC)   // 46656
#define GMIN (-4.5f)
#define INVC 4.0f               // 1 / 0.25

// Fixed-capacity buckets (ws is 256 MiB): 46656 cells x 256 x 16 B = 191 MB.
// Max observed cell count ~150 << 256; slot<CAP guard + min(cnt,CAP) keep
// accesses in-range regardless of data.
#define CAP 256

typedef float float4v __attribute__((ext_vector_type(4)));

// ws layout (bytes):
//   cnt: uint[NCELLS]          @ 0        (186,624 B; zeroed by memset)
//   bucket: float4[NCELLS*CAP] @ 186,880  (191,102,976 B)
#define WS_CNT_OFF    0
#define WS_BUCKET_OFF 186880

static __device__ __forceinline__ int cell1(float v) {
    int c = (int)floorf((v - GMIN) * INVC);
    return min(max(c, 0), NC - 1);
}

// ---------------------------------------------------------------------------
// Kernel 1: scatter means into per-cell buckets (-2x,-2y,-2z,|m|^2 --
// bit-identical transform chain to the reference einsum+d2 path).
// Also zeroes out[0] (stream-ordered before query_kernel's atomicAdds).
// ---------------------------------------------------------------------------
__global__ __launch_bounds__(256) void scatter_kernel(
    const float* __restrict__ means,
    unsigned int* __restrict__ cnt,
    float4v* __restrict__ bucket,
    float* __restrict__ out)
{
    int idx = blockIdx.x * 256 + threadIdx.x;
    if (idx == 0) out[0] = 0.0f;
    if (idx < M) {
        const float* mp = means + 3 * idx;
        float x = mp[0], y = mp[1], z = mp[2];
        int c = (cell1(z) * NC + cell1(y)) * NC + cell1(x);
        unsigned int slot = atomicAdd(&cnt[c], 1u);
        if (slot < CAP)
            bucket[(size_t)c * CAP + slot] =
                (float4v){-2.0f * x, -2.0f * y, -2.0f * z,
                          fmaf(x, x, fmaf(y, y, z * z))};
    }
}

// ---------------------------------------------------------------------------
// Kernel 2: query + loss. 1 wave/query, 4 consecutive queries per
// 256-block, (256,4), XCD chunk swizzle (consecutive same-trajectory
// queries share cells -> same XCD L2), single-group prefetch of all 27
// cell counts (independent loads, one wait), branchy clamped-slot
// gathers (round 0: slot min(lane, n-1) -- always a written slot when
// n>0, duplicates exact for min; round 1: slots 64+; round 2: rare
// n>128 tail). Per-pair arithmetic identical to the reference:
//   d' = fmaf(q2,cz, fmaf(q1,cy, fmaf(q0,cx, mm))); min; fmax(qq+mn,0).
// ---------------------------------------------------------------------------
__global__ __launch_bounds__(256, 4) void query_kernel(
    const float* __restrict__ outputs,   // [P*3]
    const float* __restrict__ c2ws,      // [64*16]
    const float* __restrict__ scales,    // [64]
    const unsigned int* __restrict__ cnt,
    const float4v* __restrict__ bucket,
    float* __restrict__ out)
{
    const int t    = threadIdx.x;
    const int lane = t & 63;
    // 1024 blocks = 8 XCDs x 128: chunk consecutive qb onto one XCD so
    // same-trajectory queries (shared cells) hit the same L2.
    const int bid = (int)blockIdx.x;
    const int qb  = (bid & 7) * 128 + (bid >> 3);
    const int qi  = qb * 4 + (t >> 6);

    // ---- query transform (all lanes redundantly; scalar-broadcast) ----
    const int b = qi >> 6;
    const float s  = scales[b];
    const float o0 = outputs[3 * qi + 0];
    const float o1 = outputs[3 * qi + 1];
    const float o2 = outputs[3 * qi + 2];
    const float* cw = c2ws + b * 16;
    float q0 = fmaf(s, fmaf(cw[0],  o0, fmaf(cw[1],  o1, cw[2]  * o2)), cw[3]);
    float q1 = fmaf(s, fmaf(cw[4],  o0, fmaf(cw[5],  o1, cw[6]  * o2)), cw[7]);
    float q2 = fmaf(s, fmaf(cw[8],  o0, fmaf(cw[9],  o1, cw[10] * o2)), cw[11]);
    float qq = fmaf(q0, q0, fmaf(q1, q1, q2 * q2));

    const int cx = cell1(q0), cy = cell1(q1), cz = cell1(q2);

    // per-axis clamped neighbor indices
    int kx[3], ky[3], kz[3];
#pragma unroll
    for (int o = 0; o < 3; ++o) {
        kx[o] = min(max(cx + o - 1, 0), NC - 1);
        ky[o] = min(max(cy + o - 1, 0), NC - 1);
        kz[o] = min(max(cz + o - 1, 0), NC - 1);
    }

    // ---- prefetch all 27 cell ids + counts (independent loads, one wait)
    int c27[27];
#pragma unroll
    for (int j = 0; j < 27; ++j) {
        const int iz = j / 9, iy = (j / 3) % 3, ix = j % 3;   // static
        c27[j] = (kz[iz] * NC + ky[iy]) * NC + kx[ix];
    }
    int n27[27];
#pragma unroll
    for (int j = 0; j < 27; ++j)
        n27[j] = min((int)cnt[c27[j]], CAP);

    int tot = 0;
#pragma unroll
    for (int j = 0; j < 27; ++j) tot += n27[j];

    float mn = 1e30f;
    if (tot > 0) {      // wave-uniform (all inputs identical across lanes)
#pragma unroll
        for (int j = 0; j < 27; ++j) {
            const int n = n27[j];
            if (n == 0) continue;                   // wave-uniform
            const float4v* row = bucket + (size_t)c27[j] * CAP;
            // round 0: clamped slot (always a written slot when n>0;
            // duplicates are real candidates -> exact for min)
            {
                float4v mv = row[min(lane, n - 1)];
                mn = fminf(mn, fmaf(q2, mv[2], fmaf(q1, mv[1],
                               fmaf(q0, mv[0], mv[3]))));
            }
            if (n > 64) {                           // wave-uniform
                float4v mv = row[min(64 + lane, n - 1)];
                mn = fminf(mn, fmaf(q2, mv[2], fmaf(q1, mv[1],
                               fmaf(q0, mv[0], mv[3]))));
            }
            if (n > 128) {                          // rare dense cells
                for (int k = 128 + lane; k < n; k += 64) {
                    float4v mv = row[k];
                    mn = fminf(mn, fmaf(q2, mv[2], fmaf(q1, mv[1],
                                   fmaf(q0, mv[0], mv[3]))));
                }
            }
        }
        // ---- fold 64 lanes ----
#pragma unroll
        for (int off = 32; off > 0; off >>= 1)
            mn = fminf(mn, __shfl_xor(mn, off, 64));
    }

    float v = 0.0f;
    if (lane == 0) {
        float d = fmaxf(qq + mn, 0.0f);   // empty neighborhood -> relu 0
        v = fmaxf(MARGIN - d, 0.0f) * (1.0f / (float)P);
    }

    // ---- block reduction (4 wave leaders), one atomicAdd per block ----
    __shared__ float red[4];
    if (lane == 0) red[t >> 6] = v;
    __syncthreads();
    if (t == 0)
        atomicAdd(out, red[0] + red[1] + red[2] + red[3]);
}

extern "C" void kernel_launch(void* const* d_in, const int* in_sizes, int n_in,
                              void* d_out, int out_size, void* d_ws, size_t ws_size,
                              hipStream_t stream) {
    const float* outputs = (const float*)d_in[0];  // (64,64,3)
    const float* c2ws    = (const float*)d_in[1];  // (64,4,4)
    const float* scales  = (const float*)d_in[2];  // (64,)
    const float* means   = (const float*)d_in[3];  // (100000,3)

    char* ws = (char*)d_ws;
    unsigned int* cnt    = (unsigned int*)(ws + WS_CNT_OFF);
    float4v*      bucket = (float4v*)(ws + WS_BUCKET_OFF);
    float*        out    = (float*)d_out;

    hipMemsetAsync(cnt, 0, NCELLS * sizeof(unsigned int), stream);
    scatter_kernel<<<(M + 255) / 256, 256, 0, stream>>>(means, cnt, bucket, out);
    query_kernel<<<P / 4, 256, 0, stream>>>(outputs, c2ws, scales,
                                            cnt, bucket, out);
}